// Round 2
// baseline (554.239 us; speedup 1.0000x reference)
//
#include <hip/hip_runtime.h>

// VectorQuantizer forward: N=131072 rows of D=64 vs K=1024 codes.
// Outputs flat fp32: [quantized_st (N*D), loss (1), indices-as-float (N)].
//
// NUMERICS FROZEN (matched np argmin with absmax 0 in round 1):
//   dist = (x2 + e2[k]) - 2*dot, dot = sequential fmaf over d=0..63,
//   argmin = strict < scanning k ascending. Do not reorder.

#define NROWS 131072
#define DIM 64
#define KCODES 1024

// loss = q_latent + 0.25 * e_latent; both equal mean((q-x)^2) in fwd
#define LOSS_SCALE (1.25f / ((float)NROWS * (float)DIM))

__global__ __launch_bounds__(256) void e2_kernel(const float* __restrict__ w,
                                                 float* __restrict__ e2) {
    int k = blockIdx.x * blockDim.x + threadIdx.x;
    if (k < KCODES) {
        const float* wk = w + k * DIM;
        float s = 0.f;
#pragma unroll
        for (int d = 0; d < DIM; ++d) s = fmaf(wk[d], wk[d], s);
        e2[k] = s;
    }
}

// min-waves-per-EU = 2: grid (512 blocks) caps us at 2 waves/SIMD anyway,
// so let the register allocator use up to 256 VGPRs -> xr[] stays resident.
__global__ __launch_bounds__(256, 2) void vq_kernel(const float* __restrict__ x,
                                                    const float* __restrict__ w,
                                                    const float* __restrict__ e2,
                                                    float* __restrict__ out_q,
                                                    float* __restrict__ out_loss,
                                                    float* __restrict__ out_idx) {
    const int row = blockIdx.x * blockDim.x + threadIdx.x;

    // Load this thread's row into registers (16 x float4)
    float xr[DIM];
    const float4* xv = (const float4*)(x + (size_t)row * DIM);
#pragma unroll
    for (int i = 0; i < DIM / 4; ++i) {
        float4 v = xv[i];
        xr[4 * i + 0] = v.x;
        xr[4 * i + 1] = v.y;
        xr[4 * i + 2] = v.z;
        xr[4 * i + 3] = v.w;
    }

    float x2 = 0.f;
#pragma unroll
    for (int d = 0; d < DIM; ++d) x2 = fmaf(xr[d], xr[d], x2);

    // Scan all K codes, 4 at a time: 4 independent fma chains hide the
    // 4-cycle VALU latency; weight addresses are wave-uniform -> s_loads.
    float best = 3.4e38f;
    int bi = 0;
    for (int k = 0; k < KCODES; k += 4) {
        const float* __restrict__ wk = w + k * DIM;
        float dot0 = 0.f, dot1 = 0.f, dot2 = 0.f, dot3 = 0.f;
#pragma unroll
        for (int d = 0; d < DIM; ++d) {
            float xd = xr[d];
            dot0 = fmaf(wk[d], xd, dot0);
            dot1 = fmaf(wk[d + DIM], xd, dot1);
            dot2 = fmaf(wk[d + 2 * DIM], xd, dot2);
            dot3 = fmaf(wk[d + 3 * DIM], xd, dot3);
        }
        // same rounding as reference: (x2 + e2) - 2*dot; strict < ascending
        float d0 = (x2 + e2[k + 0]) - 2.0f * dot0;
        float d1 = (x2 + e2[k + 1]) - 2.0f * dot1;
        float d2 = (x2 + e2[k + 2]) - 2.0f * dot2;
        float d3 = (x2 + e2[k + 3]) - 2.0f * dot3;
        if (d0 < best) { best = d0; bi = k + 0; }
        if (d1 < best) { best = d1; bi = k + 1; }
        if (d2 < best) { best = d2; bi = k + 2; }
        if (d3 < best) { best = d3; bi = k + 3; }
    }

    // Gather winning code, write quantized_st = x + (q - x), accumulate loss
    const float* __restrict__ wb = w + bi * DIM;
    float lsum = 0.f;
    float4* outv = (float4*)(out_q + (size_t)row * DIM);
#pragma unroll
    for (int i = 0; i < DIM / 4; ++i) {
        float q0 = wb[4 * i + 0], q1 = wb[4 * i + 1];
        float q2 = wb[4 * i + 2], q3 = wb[4 * i + 3];
        float d0 = q0 - xr[4 * i + 0];
        float d1 = q1 - xr[4 * i + 1];
        float d2 = q2 - xr[4 * i + 2];
        float d3 = q3 - xr[4 * i + 3];
        lsum = fmaf(d0, d0, lsum);
        lsum = fmaf(d1, d1, lsum);
        lsum = fmaf(d2, d2, lsum);
        lsum = fmaf(d3, d3, lsum);
        float4 o;
        o.x = xr[4 * i + 0] + d0;   // x + (q - x), reference STE rounding
        o.y = xr[4 * i + 1] + d1;
        o.z = xr[4 * i + 2] + d2;
        o.w = xr[4 * i + 3] + d3;
        outv[i] = o;
    }

    out_idx[row] = (float)bi;

    // Reduce loss: wave shuffle -> LDS across 4 waves -> one atomic per block
    for (int off = 32; off > 0; off >>= 1) lsum += __shfl_down(lsum, off, 64);
    __shared__ float red[4];
    const int wid = threadIdx.x >> 6;
    const int lane = threadIdx.x & 63;
    if (lane == 0) red[wid] = lsum;
    __syncthreads();
    if (threadIdx.x == 0) {
        float s = (red[0] + red[1]) + (red[2] + red[3]);
        atomicAdd(out_loss, s * LOSS_SCALE);
    }
}

extern "C" void kernel_launch(void* const* d_in, const int* in_sizes, int n_in,
                              void* d_out, int out_size, void* d_ws, size_t ws_size,
                              hipStream_t stream) {
    const float* x = (const float*)d_in[0];   // [N, D]
    const float* w = (const float*)d_in[1];   // [K, D]

    float* out_q    = (float*)d_out;                       // [N, D]
    float* out_loss = (float*)d_out + (size_t)NROWS * DIM; // [1]
    float* out_idx  = out_loss + 1;                        // [N] as floats

    float* e2 = (float*)d_ws;                              // [K]

    // zero the loss accumulator (d_out is poisoned 0xAA before every launch)
    hipMemsetAsync(out_loss, 0, sizeof(float), stream);

    e2_kernel<<<(KCODES + 255) / 256, 256, 0, stream>>>(w, e2);
    vq_kernel<<<NROWS / 256, 256, 0, stream>>>(x, w, e2, out_q, out_loss, out_idx);
}

// Round 4
// 222.803 us; speedup vs baseline: 2.4876x; 2.4876x over previous
//
#include <hip/hip_runtime.h>

// VectorQuantizer forward: N=131072 rows of D=64 vs K=1024 codes.
// Outputs flat fp32: [quantized_st (N*D), loss (1), indices-as-float (N)].
//
// Two-tier exactness scheme:
//  - vq_main: bf16 hi/lo split MFMA approx distances. Rows whose
//    (second_best - best) < MARGIN are flagged (approx error can't reorder
//    anything with a gap >= MARGIN; flagged rows get exact treatment).
//  - vq_cleanup: flagged rows re-scanned with round-1 bit-exact numerics
//    (sequential fmaf dot == np BLAS microkernel order; (x2+e2)-2*dot;
//    key-packed (dist_bits, idx) min == numpy first-index argmin).

#define NROWS 131072
#define DIM 64
#define KCODES 1024
#define MARGIN 5e-5f
#define LOSS_SCALE (1.25f / ((float)NROWS * (float)DIM))
#define BSTRIDE 72   // shorts per staged code row (64 + 8 pad -> conflict-free)

typedef short bf16x8 __attribute__((ext_vector_type(8)));
typedef float f32x4 __attribute__((ext_vector_type(4)));

__device__ __forceinline__ short f2bf(float f) {
    unsigned u = __float_as_uint(f);
    u += 0x7FFF + ((u >> 16) & 1);   // RNE
    return (short)(u >> 16);
}
__device__ __forceinline__ float bf2f(short h) {
    return __uint_as_float(((unsigned)(unsigned short)h) << 16);
}

// e2[k] via sequential fmaf (round-1-verified numerics) + bf16 hi/lo split of w
__global__ __launch_bounds__(256) void prep_w(const float* __restrict__ w,
                                              float* __restrict__ e2,
                                              short* __restrict__ w_hi,
                                              short* __restrict__ w_lo) {
    int k = blockIdx.x * blockDim.x + threadIdx.x;
    if (k >= KCODES) return;
    const float* wk = w + (size_t)k * DIM;
    float s = 0.f;
#pragma unroll
    for (int d = 0; d < DIM; ++d) {
        float f = wk[d];
        s = fmaf(f, f, s);
        short hi = f2bf(f);
        w_hi[(size_t)k * DIM + d] = hi;
        w_lo[(size_t)k * DIM + d] = f2bf(f - bf2f(hi));
    }
    e2[k] = s;
}

// Block: 4 waves x 32 rows = 128 rows. K scanned in 32-code tiles staged in LDS.
__global__ __launch_bounds__(256, 2) void vq_main(
        const float* __restrict__ x, const float* __restrict__ w,
        const float* __restrict__ e2,
        const short* __restrict__ w_hi, const short* __restrict__ w_lo,
        float* __restrict__ out_q, float* __restrict__ out_loss,
        float* __restrict__ out_idx,
        unsigned* __restrict__ flag_cnt, unsigned* __restrict__ flag_list) {
    const int tid = threadIdx.x;
    const int lane = tid & 63;
    const int wv = tid >> 6;
    const int m = lane & 15;
    const int q = lane >> 4;
    const int block_row0 = blockIdx.x * 128;
    const int wave_row0 = block_row0 + wv * 32;

    __shared__ short sb[2][32 * BSTRIDE];
    __shared__ int sidx[128];
    __shared__ unsigned char sflg[128];
    __shared__ float red[4];

    // ---- A operand: 2 rowtiles x 2 k-chunks; A[m=lane&15][k=q*8+j] ----
    float xa[2][2][8];
#pragma unroll
    for (int rt = 0; rt < 2; ++rt) {
        const float* xr = x + (size_t)(wave_row0 + rt * 16 + m) * DIM + q * 8;
        *(float4*)&xa[rt][0][0] = *(const float4*)(xr);
        *(float4*)&xa[rt][0][4] = *(const float4*)(xr + 4);
        *(float4*)&xa[rt][1][0] = *(const float4*)(xr + 32);
        *(float4*)&xa[rt][1][4] = *(const float4*)(xr + 36);
    }
    // x2 per rowtile for row rt*16+m (butterfly over quad bits)
    float x2m[2];
#pragma unroll
    for (int rt = 0; rt < 2; ++rt) {
        float s = 0.f;
#pragma unroll
        for (int c = 0; c < 2; ++c)
#pragma unroll
            for (int j = 0; j < 8; ++j) s = fmaf(xa[rt][c][j], xa[rt][c][j], s);
        s += __shfl_xor(s, 16, 64);
        s += __shfl_xor(s, 32, 64);
        x2m[rt] = s;
    }
    // remap x2 to C-layout rows: acc reg r of this lane is row rt*16 + q*4 + r
    float x2e[2][4];
#pragma unroll
    for (int rt = 0; rt < 2; ++rt)
#pragma unroll
        for (int r = 0; r < 4; ++r)
            x2e[rt][r] = __shfl(x2m[rt], (lane & 48) + q * 4 + r, 64);

    // bf16 hi/lo A fragments
    bf16x8 ah[2][2], al[2][2];
#pragma unroll
    for (int rt = 0; rt < 2; ++rt)
#pragma unroll
        for (int c = 0; c < 2; ++c)
#pragma unroll
            for (int j = 0; j < 8; ++j) {
                float f = xa[rt][c][j];
                short h = f2bf(f);
                ah[rt][c][j] = h;
                al[rt][c][j] = f2bf(f - bf2f(h));
            }

    float best[2][4], sec[2][4];
    int bidx[2][4];
#pragma unroll
    for (int rt = 0; rt < 2; ++rt)
#pragma unroll
        for (int r = 0; r < 4; ++r) {
            best[rt][r] = 3.4e38f;
            sec[rt][r] = 3.4e38f;
            bidx[rt][r] = 0;
        }

    for (int t = 0; t < KCODES / 32; ++t) {
        __syncthreads();   // prior tile fully consumed
        // stage 32 codes (hi+lo) : 512 chunks of 16B, 2 per thread
#pragma unroll
        for (int i = 0; i < 2; ++i) {
            int ch = tid + i * 256;
            int arr = ch >> 8;
            int code = (ch >> 3) & 31;
            int seg = ch & 7;
            const short* src = (arr ? w_lo : w_hi) +
                               ((size_t)(t * 32 + code)) * DIM + seg * 8;
            *(bf16x8*)&sb[arr][code * BSTRIDE + seg * 8] = *(const bf16x8*)src;
        }
        __syncthreads();

        // B frags: B[k=kc*32+q*8+j][n=ct*16+m]
        bf16x8 bh[2][2], bl[2][2];
#pragma unroll
        for (int ct = 0; ct < 2; ++ct)
#pragma unroll
            for (int kc = 0; kc < 2; ++kc) {
                int off = (ct * 16 + m) * BSTRIDE + kc * 32 + q * 8;
                bh[ct][kc] = *(bf16x8*)&sb[0][off];
                bl[ct][kc] = *(bf16x8*)&sb[1][off];
            }

        f32x4 acc[2][2];
#pragma unroll
        for (int rt = 0; rt < 2; ++rt)
#pragma unroll
            for (int ct = 0; ct < 2; ++ct) {
                f32x4 a = {0.f, 0.f, 0.f, 0.f};
                a = __builtin_amdgcn_mfma_f32_16x16x32_bf16(al[rt][0], bh[ct][0], a, 0, 0, 0);
                a = __builtin_amdgcn_mfma_f32_16x16x32_bf16(ah[rt][0], bl[ct][0], a, 0, 0, 0);
                a = __builtin_amdgcn_mfma_f32_16x16x32_bf16(ah[rt][0], bh[ct][0], a, 0, 0, 0);
                a = __builtin_amdgcn_mfma_f32_16x16x32_bf16(al[rt][1], bh[ct][1], a, 0, 0, 0);
                a = __builtin_amdgcn_mfma_f32_16x16x32_bf16(ah[rt][1], bl[ct][1], a, 0, 0, 0);
                a = __builtin_amdgcn_mfma_f32_16x16x32_bf16(ah[rt][1], bh[ct][1], a, 0, 0, 0);
                acc[rt][ct] = a;
            }

        float e2c0 = e2[t * 32 + m];
        float e2c1 = e2[t * 32 + 16 + m];
#pragma unroll
        for (int rt = 0; rt < 2; ++rt)
#pragma unroll
            for (int ct = 0; ct < 2; ++ct) {   // ct ascending: idx ascending
                float e2c = ct ? e2c1 : e2c0;
                int id = t * 32 + ct * 16 + m;
#pragma unroll
                for (int r = 0; r < 4; ++r) {
                    float d = fmaf(-2.f, acc[rt][ct][r], x2e[rt][r] + e2c);
                    bool c = d < best[rt][r];
                    sec[rt][r] = fminf(sec[rt][r], fmaxf(d, best[rt][r]));
                    if (c) { best[rt][r] = d; bidx[rt][r] = id; }
                }
            }
    }

    // cross-lane reduce over the 16 codes-lanes (same q group), tie -> lower idx
#pragma unroll
    for (int off = 1; off < 16; off <<= 1)
#pragma unroll
        for (int rt = 0; rt < 2; ++rt)
#pragma unroll
            for (int r = 0; r < 4; ++r) {
                float ob = __shfl_xor(best[rt][r], off, 64);
                int oi = __shfl_xor(bidx[rt][r], off, 64);
                float os = __shfl_xor(sec[rt][r], off, 64);
                float mx = fmaxf(best[rt][r], ob);
                sec[rt][r] = fminf(fminf(sec[rt][r], os), mx);
                bool take = (ob < best[rt][r]) ||
                            (ob == best[rt][r] && oi < bidx[rt][r]);
                if (take) { best[rt][r] = ob; bidx[rt][r] = oi; }
            }

    if (m == 0) {
#pragma unroll
        for (int rt = 0; rt < 2; ++rt)
#pragma unroll
            for (int r = 0; r < 4; ++r) {
                int lr = wv * 32 + rt * 16 + q * 4 + r;
                sidx[lr] = bidx[rt][r];
                bool fl = (sec[rt][r] - best[rt][r]) < MARGIN;
                sflg[lr] = fl ? 1 : 0;
                if (fl) {
                    unsigned p = atomicAdd(flag_cnt, 1u);
                    flag_list[p] = (unsigned)(block_row0 + lr);
                }
            }
    }
    __syncthreads();

    // ---- output pass: 2 x 64 rows, 4 threads/row ----
    float lsum = 0.f;
    const int rl = tid >> 2, part = tid & 3;
#pragma unroll
    for (int p = 0; p < 2; ++p) {
        int lr = p * 64 + rl;
        int grow = block_row0 + lr;
        if (!sflg[lr]) {
            int bi = sidx[lr];
            const float* xs = x + (size_t)grow * DIM + part * 16;
            const float* ws = w + (size_t)bi * DIM + part * 16;
            float* os = out_q + (size_t)grow * DIM + part * 16;
#pragma unroll
            for (int i = 0; i < 4; ++i) {
                float4 xv = *(const float4*)(xs + 4 * i);
                float4 wv4 = *(const float4*)(ws + 4 * i);
                float d0 = wv4.x - xv.x, d1 = wv4.y - xv.y;
                float d2 = wv4.z - xv.z, d3 = wv4.w - xv.w;
                lsum = fmaf(d0, d0, lsum);
                lsum = fmaf(d1, d1, lsum);
                lsum = fmaf(d2, d2, lsum);
                lsum = fmaf(d3, d3, lsum);
                float4 o = {xv.x + d0, xv.y + d1, xv.z + d2, xv.w + d3};
                *(float4*)(os + 4 * i) = o;
            }
            if (part == 0) out_idx[grow] = (float)bi;
        }
    }

    for (int off = 32; off > 0; off >>= 1) lsum += __shfl_down(lsum, off, 64);
    if ((tid & 63) == 0) red[tid >> 6] = lsum;
    __syncthreads();
    if (tid == 0) {
        float s = (red[0] + red[1]) + (red[2] + red[3]);
        atomicAdd(out_loss, s * LOSS_SCALE);
    }
}

// Exact re-scan of flagged rows: 16 rows per block-chunk, full 1024 codes,
// round-1 numerics, key-min argmin (== numpy first-index rule).
#define CH 16
__global__ __launch_bounds__(256) void vq_cleanup(
        const float* __restrict__ x, const float* __restrict__ w,
        const float* __restrict__ e2,
        const unsigned* __restrict__ flag_cnt,
        const unsigned* __restrict__ flag_list,
        float* __restrict__ out_q, float* __restrict__ out_loss,
        float* __restrict__ out_idx) {
    __shared__ float xs[CH][68];
    __shared__ float wt[128][68];
    __shared__ float sx2[CH];
    const int tid = threadIdx.x;
    const int rowsub = tid >> 4;    // 0..15
    const int kslot = tid & 15;
    const unsigned cnt = *flag_cnt;

    for (unsigned base = blockIdx.x * CH; base < cnt; base += gridDim.x * CH) {
        const int nrows = (int)min((unsigned)CH, cnt - base);
        __syncthreads();   // protect LDS reuse
        {   // load x rows: 16 float4 per row
            int rr = tid >> 4, sg = tid & 15;
            if (rr < nrows) {
                unsigned grow = flag_list[base + rr];
                *(float4*)&xs[rr][sg * 4] =
                    *(const float4*)(x + (size_t)grow * DIM + sg * 4);
            }
        }
        __syncthreads();
        if (tid < nrows) {
            float s = 0.f;
#pragma unroll
            for (int d = 0; d < DIM; ++d) s = fmaf(xs[tid][d], xs[tid][d], s);
            sx2[tid] = s;
        }

        unsigned long long kmin = ~0ULL;
        for (int tile = 0; tile < KCODES / 128; ++tile) {
            __syncthreads();
#pragma unroll
            for (int i = 0; i < 8; ++i) {   // 2048 float4s, 8 per thread
                int f = tid + i * 256;
                int code = f >> 4, sg = f & 15;
                *(float4*)&wt[code][sg * 4] =
                    *(const float4*)(w + (size_t)(tile * 128 + code) * DIM + sg * 4);
            }
            __syncthreads();
            if (rowsub < nrows) {
#pragma unroll
                for (int j = 0; j < 8; ++j) {
                    int cl = j * 16 + kslot;
                    int code = tile * 128 + cl;
                    float dot = 0.f;
#pragma unroll
                    for (int d = 0; d < DIM; ++d)
                        dot = fmaf(wt[cl][d], xs[rowsub][d], dot);
                    float dist = (sx2[rowsub] + e2[code]) - 2.0f * dot;
                    unsigned long long key =
                        ((unsigned long long)__float_as_uint(dist) << 32) |
                        (unsigned)code;
                    kmin = kmin < key ? kmin : key;
                }
            }
        }
        // reduce over the row's 16 contiguous lanes
#pragma unroll
        for (int off = 1; off < 16; off <<= 1) {
            unsigned long long o = __shfl_xor(kmin, off, 64);
            kmin = kmin < o ? kmin : o;
        }
        if (rowsub < nrows) {
            unsigned long long kk = __shfl(kmin, (tid & 63) & ~15, 64);
            int bi = (int)(unsigned)(kk & 0xFFFFFFFFu);
            unsigned grow = flag_list[base + rowsub];
            float4 x4 = *(float4*)&xs[rowsub][kslot * 4];
            float4 w4 = *(const float4*)(w + (size_t)bi * DIM + kslot * 4);
            float d0 = w4.x - x4.x, d1 = w4.y - x4.y;
            float d2 = w4.z - x4.z, d3 = w4.w - x4.w;
            float ls = 0.f;
            ls = fmaf(d0, d0, ls);
            ls = fmaf(d1, d1, ls);
            ls = fmaf(d2, d2, ls);
            ls = fmaf(d3, d3, ls);
            float4 o = {x4.x + d0, x4.y + d1, x4.z + d2, x4.w + d3};
            *(float4*)(out_q + (size_t)grow * DIM + kslot * 4) = o;
            if (kslot == 0) out_idx[grow] = (float)bi;
#pragma unroll
            for (int off = 1; off < 16; off <<= 1)
                ls += __shfl_xor(ls, off, 64);
            if (kslot == 0) atomicAdd(out_loss, ls * LOSS_SCALE);
        }
    }
}

extern "C" void kernel_launch(void* const* d_in, const int* in_sizes, int n_in,
                              void* d_out, int out_size, void* d_ws, size_t ws_size,
                              hipStream_t stream) {
    const float* x = (const float*)d_in[0];   // [N, D]
    const float* w = (const float*)d_in[1];   // [K, D]

    float* out_q    = (float*)d_out;
    float* out_loss = (float*)d_out + (size_t)NROWS * DIM;
    float* out_idx  = out_loss + 1;

    // ws: e2 (4KB) | w_hi (128KB) | w_lo (128KB) | cnt (4B) | list (512KB)
    float* e2 = (float*)d_ws;
    short* w_hi = (short*)(e2 + KCODES);
    short* w_lo = w_hi + (size_t)KCODES * DIM;
    unsigned* cnt = (unsigned*)(w_lo + (size_t)KCODES * DIM);
    unsigned* list = cnt + 1;

    hipMemsetAsync(out_loss, 0, sizeof(float), stream);
    hipMemsetAsync(cnt, 0, sizeof(unsigned), stream);

    prep_w<<<(KCODES + 255) / 256, 256, 0, stream>>>(w, e2, w_hi, w_lo);
    vq_main<<<NROWS / 128, 256, 0, stream>>>(x, w, e2, w_hi, w_lo,
                                             out_q, out_loss, out_idx, cnt, list);
    vq_cleanup<<<512, 256, 0, stream>>>(x, w, e2, cnt, list,
                                        out_q, out_loss, out_idx);
}

// Round 5
// 208.709 us; speedup vs baseline: 2.6556x; 1.0675x over previous
//
#include <hip/hip_runtime.h>

// VectorQuantizer forward: N=131072 rows of D=64 vs K=1024 codes.
// Outputs flat fp32: [quantized_st (N*D), loss (1), indices-as-float (N)].
//
// Two-tier exactness scheme (validated round 4, absmax 0):
//  - vq_main: bf16 hi/lo split MFMA approx of g[k] = e2[k] - 2*dot (x2 dropped:
//    argmin and the best/second gap are invariant to the per-row constant).
//    Rows with (sec - best) < MARGIN are flagged for exact treatment.
//  - vq_cleanup: flagged rows re-scanned with round-1 bit-exact numerics
//    (sequential fmaf dot, (x2+e2)-2*dot, key-packed (dist,idx) min).
// B-matrix is pre-swizzled into MFMA fragment order so the K-loop has NO LDS
// and NO barriers: each lane reads its B-frags as contiguous global b128 loads.

#define NROWS 131072
#define DIM 64
#define KCODES 1024
#define MARGIN 5e-5f
#define LOSS_SCALE (1.25f / ((float)NROWS * (float)DIM))

typedef short bf16x8 __attribute__((ext_vector_type(8)));
typedef float f32x4 __attribute__((ext_vector_type(4)));

__device__ __forceinline__ short f2bf(float f) {
    unsigned u = __float_as_uint(f);
    u += 0x7FFF + ((u >> 16) & 1);   // RNE
    return (short)(u >> 16);
}
__device__ __forceinline__ float bf2f(short h) {
    return __uint_as_float(((unsigned)(unsigned short)h) << 16);
}

// Per code k: e2[k] by sequential fmaf (bit-pattern the cleanup relies on),
// plus bf16 hi/lo split of w stored in MFMA B-frag order:
//   short index = ((((t*2+ct)*2+kc)*4+q)*16 + m)*8 + j
//   where k = t*32 + ct*16 + m, d = kc*32 + q*8 + j.
__global__ __launch_bounds__(256) void prep_w(const float* __restrict__ w,
                                              float* __restrict__ e2,
                                              short* __restrict__ w_hi,
                                              short* __restrict__ w_lo) {
    int k = blockIdx.x * blockDim.x + threadIdx.x;
    if (k >= KCODES) return;
    const float* wk = w + (size_t)k * DIM;
    float r[DIM];
#pragma unroll
    for (int i = 0; i < DIM / 4; ++i) *(float4*)&r[4 * i] = *(const float4*)(wk + 4 * i);
    float s = 0.f;
#pragma unroll
    for (int d = 0; d < DIM; ++d) s = fmaf(r[d], r[d], s);
    e2[k] = s;

    const int t = k >> 5, ct = (k >> 4) & 1, m = k & 15;
#pragma unroll
    for (int kc = 0; kc < 2; ++kc)
#pragma unroll
        for (int q = 0; q < 4; ++q) {
            bf16x8 hv, lv;
#pragma unroll
            for (int j = 0; j < 8; ++j) {
                float f = r[kc * 32 + q * 8 + j];
                short h = f2bf(f);
                hv[j] = h;
                lv[j] = f2bf(f - bf2f(h));
            }
            size_t fo = ((size_t)(((t * 2 + ct) * 2 + kc) * 4 + q) * 16 + m) * 8;
            *(bf16x8*)(w_hi + fo) = hv;
            *(bf16x8*)(w_lo + fo) = lv;
        }
}

// Block: 4 independent waves x 32 rows = 128 rows. No barriers in the K-loop.
__global__ __launch_bounds__(256, 3) void vq_main(
        const float* __restrict__ x, const float* __restrict__ w,
        const float* __restrict__ e2,
        const short* __restrict__ w_hi, const short* __restrict__ w_lo,
        float* __restrict__ out_q, float* __restrict__ out_loss,
        float* __restrict__ out_idx,
        unsigned* __restrict__ flag_cnt, unsigned* __restrict__ flag_list) {
    const int tid = threadIdx.x;
    const int lane = tid & 63;
    const int wv = tid >> 6;
    const int m = lane & 15;
    const int q = lane >> 4;
    const int block_row0 = blockIdx.x * 128;
    const int wave_row0 = block_row0 + wv * 32;

    __shared__ int sidx[128];
    __shared__ unsigned char sflg[128];
    __shared__ float red[4];

    // ---- A operand: 2 rowtiles x 2 k-chunks; A[m][k=q*8+j] ----
    float xa[2][2][8];
#pragma unroll
    for (int rt = 0; rt < 2; ++rt) {
        const float* xr = x + (size_t)(wave_row0 + rt * 16 + m) * DIM + q * 8;
        *(float4*)&xa[rt][0][0] = *(const float4*)(xr);
        *(float4*)&xa[rt][0][4] = *(const float4*)(xr + 4);
        *(float4*)&xa[rt][1][0] = *(const float4*)(xr + 32);
        *(float4*)&xa[rt][1][4] = *(const float4*)(xr + 36);
    }
    bf16x8 ah[2][2], al[2][2];
#pragma unroll
    for (int rt = 0; rt < 2; ++rt)
#pragma unroll
        for (int c = 0; c < 2; ++c)
#pragma unroll
            for (int j = 0; j < 8; ++j) {
                float f = xa[rt][c][j];
                short h = f2bf(f);
                ah[rt][c][j] = h;
                al[rt][c][j] = f2bf(f - bf2f(h));
            }

    float best[2][4], sec[2][4];
    int bidx[2][4];
#pragma unroll
    for (int rt = 0; rt < 2; ++rt)
#pragma unroll
        for (int r = 0; r < 4; ++r) {
            best[rt][r] = 3.4e38f;
            sec[rt][r] = 3.4e38f;
            bidx[rt][r] = 0;
        }

    // Per-lane B pointers into frag-ordered arrays; tile stride 2048 shorts.
    const short* ph = w_hi + q * 128 + m * 8;
    const short* pl = w_lo + q * 128 + m * 8;

    for (int t = 0; t < KCODES / 32; ++t) {
        bf16x8 bh[2][2], bl[2][2];
#pragma unroll
        for (int ct = 0; ct < 2; ++ct)
#pragma unroll
            for (int kc = 0; kc < 2; ++kc) {
                int off = t * 2048 + (ct * 2 + kc) * 512;
                bh[ct][kc] = *(const bf16x8*)(ph + off);
                bl[ct][kc] = *(const bf16x8*)(pl + off);
            }
        float e2c0 = e2[t * 32 + m];
        float e2c1 = e2[t * 32 + 16 + m];

        f32x4 acc[2][2];
#pragma unroll
        for (int rt = 0; rt < 2; ++rt)
#pragma unroll
            for (int ct = 0; ct < 2; ++ct) {
                f32x4 a = {0.f, 0.f, 0.f, 0.f};
                a = __builtin_amdgcn_mfma_f32_16x16x32_bf16(al[rt][0], bh[ct][0], a, 0, 0, 0);
                a = __builtin_amdgcn_mfma_f32_16x16x32_bf16(ah[rt][0], bl[ct][0], a, 0, 0, 0);
                a = __builtin_amdgcn_mfma_f32_16x16x32_bf16(ah[rt][0], bh[ct][0], a, 0, 0, 0);
                a = __builtin_amdgcn_mfma_f32_16x16x32_bf16(al[rt][1], bh[ct][1], a, 0, 0, 0);
                a = __builtin_amdgcn_mfma_f32_16x16x32_bf16(ah[rt][1], bl[ct][1], a, 0, 0, 0);
                a = __builtin_amdgcn_mfma_f32_16x16x32_bf16(ah[rt][1], bh[ct][1], a, 0, 0, 0);
                acc[rt][ct] = a;
            }

#pragma unroll
        for (int rt = 0; rt < 2; ++rt)
#pragma unroll
            for (int ct = 0; ct < 2; ++ct) {   // ct ascending: idx ascending
                float e2c = ct ? e2c1 : e2c0;
                int id = t * 32 + ct * 16 + m;
#pragma unroll
                for (int r = 0; r < 4; ++r) {
                    float g = fmaf(-2.f, acc[rt][ct][r], e2c);
                    bool c = g < best[rt][r];
                    sec[rt][r] = fminf(sec[rt][r], fmaxf(g, best[rt][r]));
                    if (c) { best[rt][r] = g; bidx[rt][r] = id; }
                }
            }
    }

    // cross-lane reduce over the 16 m-lanes; tie -> lower idx (numpy rule)
#pragma unroll
    for (int off = 1; off < 16; off <<= 1)
#pragma unroll
        for (int rt = 0; rt < 2; ++rt)
#pragma unroll
            for (int r = 0; r < 4; ++r) {
                float ob = __shfl_xor(best[rt][r], off, 64);
                int oi = __shfl_xor(bidx[rt][r], off, 64);
                float os = __shfl_xor(sec[rt][r], off, 64);
                float mx = fmaxf(best[rt][r], ob);
                sec[rt][r] = fminf(fminf(sec[rt][r], os), mx);
                bool take = (ob < best[rt][r]) ||
                            (ob == best[rt][r] && oi < bidx[rt][r]);
                if (take) { best[rt][r] = ob; bidx[rt][r] = oi; }
            }

    if (m == 0) {
#pragma unroll
        for (int rt = 0; rt < 2; ++rt)
#pragma unroll
            for (int r = 0; r < 4; ++r) {
                int lr = wv * 32 + rt * 16 + q * 4 + r;
                sidx[lr] = bidx[rt][r];
                bool fl = (sec[rt][r] - best[rt][r]) < MARGIN;
                sflg[lr] = fl ? 1 : 0;
                if (fl) {
                    unsigned p = atomicAdd(flag_cnt, 1u);
                    flag_list[p] = (unsigned)(block_row0 + lr);
                }
            }
    }
    __syncthreads();

    // ---- output pass: 2 x 64 rows, 4 threads/row ----
    float lsum = 0.f;
    const int rl = tid >> 2, part = tid & 3;
#pragma unroll
    for (int p = 0; p < 2; ++p) {
        int lr = p * 64 + rl;
        int grow = block_row0 + lr;
        if (!sflg[lr]) {
            int bi = sidx[lr];
            const float* xs = x + (size_t)grow * DIM + part * 16;
            const float* ws = w + (size_t)bi * DIM + part * 16;
            float* os = out_q + (size_t)grow * DIM + part * 16;
#pragma unroll
            for (int i = 0; i < 4; ++i) {
                float4 xv = *(const float4*)(xs + 4 * i);
                float4 wv4 = *(const float4*)(ws + 4 * i);
                float d0 = wv4.x - xv.x, d1 = wv4.y - xv.y;
                float d2 = wv4.z - xv.z, d3 = wv4.w - xv.w;
                lsum = fmaf(d0, d0, lsum);
                lsum = fmaf(d1, d1, lsum);
                lsum = fmaf(d2, d2, lsum);
                lsum = fmaf(d3, d3, lsum);
                float4 o = {xv.x + d0, xv.y + d1, xv.z + d2, xv.w + d3};
                *(float4*)(os + 4 * i) = o;
            }
            if (part == 0) out_idx[grow] = (float)bi;
        }
    }

    for (int off = 32; off > 0; off >>= 1) lsum += __shfl_down(lsum, off, 64);
    if ((tid & 63) == 0) red[tid >> 6] = lsum;
    __syncthreads();
    if (tid == 0) {
        float s = (red[0] + red[1]) + (red[2] + red[3]);
        atomicAdd(out_loss, s * LOSS_SCALE);
    }
}

// Exact re-scan of flagged rows (round-1 numerics). b128 LDS reads; the fmaf
// chain stays in ascending-d order -> bit-identical dots.
#define CH 16
__global__ __launch_bounds__(256) void vq_cleanup(
        const float* __restrict__ x, const float* __restrict__ w,
        const float* __restrict__ e2,
        const unsigned* __restrict__ flag_cnt,
        const unsigned* __restrict__ flag_list,
        float* __restrict__ out_q, float* __restrict__ out_loss,
        float* __restrict__ out_idx) {
    __shared__ float xs[CH][68];
    __shared__ float wt[128][68];
    __shared__ float sx2[CH];
    const int tid = threadIdx.x;
    const int rowsub = tid >> 4;    // 0..15
    const int kslot = tid & 15;
    const unsigned cnt = *flag_cnt;

    for (unsigned base = blockIdx.x * CH; base < cnt; base += gridDim.x * CH) {
        const int nrows = (int)min((unsigned)CH, cnt - base);
        __syncthreads();
        {
            int rr = tid >> 4, sg = tid & 15;
            if (rr < nrows) {
                unsigned grow = flag_list[base + rr];
                *(float4*)&xs[rr][sg * 4] =
                    *(const float4*)(x + (size_t)grow * DIM + sg * 4);
            }
        }
        __syncthreads();
        if (tid < nrows) {
            float s = 0.f;
#pragma unroll
            for (int d = 0; d < DIM; ++d) s = fmaf(xs[tid][d], xs[tid][d], s);
            sx2[tid] = s;
        }

        unsigned long long kmin = ~0ULL;
        for (int tile = 0; tile < KCODES / 128; ++tile) {
            __syncthreads();
#pragma unroll
            for (int i = 0; i < 8; ++i) {
                int f = tid + i * 256;
                int code = f >> 4, sg = f & 15;
                *(float4*)&wt[code][sg * 4] =
                    *(const float4*)(w + (size_t)(tile * 128 + code) * DIM + sg * 4);
            }
            __syncthreads();
            if (rowsub < nrows) {
#pragma unroll
                for (int j = 0; j < 8; ++j) {
                    int cl = j * 16 + kslot;
                    int code = tile * 128 + cl;
                    float dot = 0.f;
#pragma unroll
                    for (int d4 = 0; d4 < 16; ++d4) {
                        float4 wv4 = *(const float4*)&wt[cl][d4 * 4];
                        float4 xv4 = *(const float4*)&xs[rowsub][d4 * 4];
                        dot = fmaf(wv4.x, xv4.x, dot);
                        dot = fmaf(wv4.y, xv4.y, dot);
                        dot = fmaf(wv4.z, xv4.z, dot);
                        dot = fmaf(wv4.w, xv4.w, dot);
                    }
                    float dist = (sx2[rowsub] + e2[code]) - 2.0f * dot;
                    unsigned long long key =
                        ((unsigned long long)__float_as_uint(dist) << 32) |
                        (unsigned)code;
                    kmin = kmin < key ? kmin : key;
                }
            }
        }
#pragma unroll
        for (int off = 1; off < 16; off <<= 1) {
            unsigned long long o = __shfl_xor(kmin, off, 64);
            kmin = kmin < o ? kmin : o;
        }
        if (rowsub < nrows) {
            int bi = (int)(unsigned)(kmin & 0xFFFFFFFFu);
            unsigned grow = flag_list[base + rowsub];
            float4 x4 = *(float4*)&xs[rowsub][kslot * 4];
            float4 w4 = *(const float4*)(w + (size_t)bi * DIM + kslot * 4);
            float d0 = w4.x - x4.x, d1 = w4.y - x4.y;
            float d2 = w4.z - x4.z, d3 = w4.w - x4.w;
            float ls = 0.f;
            ls = fmaf(d0, d0, ls);
            ls = fmaf(d1, d1, ls);
            ls = fmaf(d2, d2, ls);
            ls = fmaf(d3, d3, ls);
            float4 o = {x4.x + d0, x4.y + d1, x4.z + d2, x4.w + d3};
            *(float4*)(out_q + (size_t)grow * DIM + kslot * 4) = o;
            if (kslot == 0) out_idx[grow] = (float)bi;
#pragma unroll
            for (int off = 1; off < 16; off <<= 1)
                ls += __shfl_xor(ls, off, 64);
            if (kslot == 0) atomicAdd(out_loss, ls * LOSS_SCALE);
        }
    }
}

extern "C" void kernel_launch(void* const* d_in, const int* in_sizes, int n_in,
                              void* d_out, int out_size, void* d_ws, size_t ws_size,
                              hipStream_t stream) {
    const float* x = (const float*)d_in[0];   // [N, D]
    const float* w = (const float*)d_in[1];   // [K, D]

    float* out_q    = (float*)d_out;
    float* out_loss = (float*)d_out + (size_t)NROWS * DIM;
    float* out_idx  = out_loss + 1;

    // ws: e2 (4KB) | w_hi frag-order (128KB) | w_lo (128KB) | cnt | list (512KB)
    float* e2 = (float*)d_ws;
    short* w_hi = (short*)(e2 + KCODES);
    short* w_lo = w_hi + (size_t)KCODES * DIM;
    unsigned* cnt = (unsigned*)(w_lo + (size_t)KCODES * DIM);
    unsigned* list = cnt + 1;

    hipMemsetAsync(out_loss, 0, sizeof(float), stream);
    hipMemsetAsync(cnt, 0, sizeof(unsigned), stream);

    prep_w<<<(KCODES + 255) / 256, 256, 0, stream>>>(w, e2, w_hi, w_lo);
    vq_main<<<NROWS / 128, 256, 0, stream>>>(x, w, e2, w_hi, w_lo,
                                             out_q, out_loss, out_idx, cnt, list);
    vq_cleanup<<<256, 256, 0, stream>>>(x, w, e2, cnt, list,
                                        out_q, out_loss, out_idx);
}